// Round 1
// baseline (699.261 us; speedup 1.0000x reference)
//
#include <hip/hip_runtime.h>
#include <stdint.h>

// Problem constants: B=4, N=4096, E=128, H=8, D=16, FF=512
// Heads never mix across the E axis -> treat everything as [B*N, 128].

typedef __attribute__((ext_vector_type(8))) short short8;   // 8 bf16 (4 VGPRs)
typedef __attribute__((ext_vector_type(4))) float f32x4;

__device__ __forceinline__ uint16_t f2bf(float f) {
    uint32_t u = __builtin_bit_cast(uint32_t, f);
    u += 0x7fffu + ((u >> 16) & 1u);   // RNE
    return (uint16_t)(u >> 16);
}
__device__ __forceinline__ float bf2f(uint16_t h) {
    uint32_t u = ((uint32_t)h) << 16;
    return __builtin_bit_cast(float, u);
}
__device__ __forceinline__ f32x4 mfma16(short8 a, short8 b, f32x4 c) {
    return __builtin_amdgcn_mfma_f32_16x16x32_bf16(a, b, c, 0, 0, 0);
}

// ---------------------------------------------------------------- k_prep
__global__ __launch_bounds__(256) void k_prep(
    const float* __restrict__ Wq, const float* __restrict__ Wk,
    const float* __restrict__ Wv, const float* __restrict__ Wo,
    const float* __restrict__ W1, const float* __restrict__ W2,
    uint16_t* __restrict__ wqkvT, uint16_t* __restrict__ woT,
    uint16_t* __restrict__ w1T, uint16_t* __restrict__ w2T) {
    int t = blockIdx.x * 256 + threadIdx.x;
    if (t < 49152) {                       // wqkvT[n][k], n in [0,384)
        int n = t >> 7, k = t & 127;
        const float* W = (n < 128) ? Wq : (n < 256) ? Wk : Wv;
        wqkvT[t] = f2bf(W[k * 128 + (n & 127)]);
    } else if (t < 65536) {                // woT[e][d] = Wo[d][e]
        int i = t - 49152; int e = i >> 7, d = i & 127;
        woT[i] = f2bf(Wo[d * 128 + e]);
    } else if (t < 131072) {               // w1T[f][e] = W1[e][f]
        int i = t - 65536; int f = i >> 7, e = i & 127;
        w1T[i] = f2bf(W1[e * 512 + f]);
    } else if (t < 196608) {               // w2T[e][f] = W2[f][e]
        int i = t - 131072; int e = i >> 9, f = i & 511;
        w2T[i] = f2bf(W2[f * 128 + e]);
    }
}

// ---------------------------------------------------------------- k_rms
__global__ __launch_bounds__(256) void k_rms(
    const float* __restrict__ x, const float* __restrict__ g,
    uint16_t* __restrict__ o) {
    int row = blockIdx.x * 4 + (threadIdx.x >> 6);
    int l = threadIdx.x & 63;
    float2 v = *(const float2*)(x + (size_t)row * 128 + l * 2);
    float ss = v.x * v.x + v.y * v.y;
    #pragma unroll
    for (int m = 32; m >= 1; m >>= 1) ss += __shfl_xor(ss, m, 64);
    float rs = rsqrtf(ss * (1.0f / 128.0f) + 1e-6f);
    float2 gv = *(const float2*)(g + l * 2);
    uint32_t lo = (uint32_t)f2bf(v.x * rs * gv.x) |
                  ((uint32_t)f2bf(v.y * rs * gv.y) << 16);
    *(uint32_t*)(o + (size_t)row * 128 + l * 2) = lo;
}

// ---------------------------------------------------------------- k_qkv
// [64 x 128] h-tile @ [128 x 384] Wqkv. 6 waves, each 64x64.
// Epilogue: sigq = sigmoid(q) (bf16), McatT[b][col][i] = [exp(k)*v | exp(k)].
__global__ __launch_bounds__(384) void k_qkv(
    const uint16_t* __restrict__ h, const uint16_t* __restrict__ wqkvT,
    uint16_t* __restrict__ sigq, uint16_t* __restrict__ mcatT) {
    __shared__ __align__(16) char sm[65536];
    uint16_t* Al = (uint16_t*)sm;   // 64 x 136 bf16
    float*    Pl = (float*)sm;      // 64 x 256 f32, after K-loop
    const int t = threadIdx.x;
    const int i0 = blockIdx.x * 64;
    for (int idx = t; idx < 1024; idx += 384) {
        int row = idx >> 4, c8 = (idx & 15) * 8;
        *(uint4*)&Al[row * 136 + c8] =
            *(const uint4*)(h + (size_t)(i0 + row) * 128 + c8);
    }
    __syncthreads();
    const int w = t >> 6, l = t & 63, ml = l & 15, qd = l >> 4;
    f32x4 acc[4][4];
    f32x4 zv = {0.f, 0.f, 0.f, 0.f};
    #pragma unroll
    for (int a = 0; a < 4; ++a)
        #pragma unroll
        for (int b = 0; b < 4; ++b) acc[a][b] = zv;
    #pragma unroll
    for (int kc = 0; kc < 4; ++kc) {
        short8 af[4], bfr[4];
        #pragma unroll
        for (int fm = 0; fm < 4; ++fm)
            af[fm] = *(const short8*)&Al[(fm * 16 + ml) * 136 + kc * 32 + qd * 8];
        #pragma unroll
        for (int fn = 0; fn < 4; ++fn)
            bfr[fn] = *(const short8*)(wqkvT + (w * 64 + fn * 16 + ml) * 128 + kc * 32 + qd * 8);
        #pragma unroll
        for (int fm = 0; fm < 4; ++fm)
            #pragma unroll
            for (int fn = 0; fn < 4; ++fn)
                acc[fm][fn] = mfma16(af[fm], bfr[fn], acc[fm][fn]);
    }
    __syncthreads();
    const int bb = i0 >> 12, il0 = i0 & 4095;
    if (w < 2) {       // q columns -> sigmoid, straight to global
        #pragma unroll
        for (int fm = 0; fm < 4; ++fm)
            #pragma unroll
            for (int fn = 0; fn < 4; ++fn)
                #pragma unroll
                for (int r = 0; r < 4; ++r) {
                    int row = fm * 16 + qd * 4 + r;
                    int col = w * 64 + fn * 16 + ml;
                    sigq[(size_t)(i0 + row) * 128 + col] =
                        f2bf(1.f / (1.f + __expf(-acc[fm][fn][r])));
                }
    } else {           // k -> exp(k) at Pl cols [0,128); v raw at [128,256)
        int half = (w < 4) ? 0 : 1;
        int cbase = (w - (half ? 4 : 2)) * 64;
        #pragma unroll
        for (int fm = 0; fm < 4; ++fm)
            #pragma unroll
            for (int fn = 0; fn < 4; ++fn)
                #pragma unroll
                for (int r = 0; r < 4; ++r) {
                    int row = fm * 16 + qd * 4 + r;
                    int col = cbase + fn * 16 + ml;
                    float vv = acc[fm][fn][r];
                    if (!half) vv = __expf(vv);
                    Pl[row * 256 + half * 128 + ((col + row) & 127)] = vv;
                }
    }
    __syncthreads();
    for (int idx = t; idx < 16384; idx += 384) {
        int cc = idx >> 6, il = idx & 63;
        int pc = ((cc & 127) + il) & 127;
        float ekw = Pl[il * 256 + pc];
        float val = (cc < 128) ? ekw * Pl[il * 256 + 128 + pc] : ekw;
        mcatT[((size_t)bb * 256 + cc) * 4096 + il0 + il] = f2bf(val);
    }
}

// ---------------------------------------------------------------- k_mega
// Fuses k_big + k_att + rmsnorm2. Per (j-tile of 32, batch):
//   P[32 x 256] = sum_i exp(c*dis[i][j]) * Mcat[i][col]   (full K=4096)
//   att = sigq * (P[:, :128] / P[:, 128:])                (bf16)
//   out1 = x + att @ Wo ; h2 = rmsnorm(out1, g_post)
// 512 blocks -> 2 blocks/CU for inter-block latency hiding; next K-step's
// dis/mcat loads issued before the MFMA phase (register prefetch).
__global__ __launch_bounds__(512, 4) void k_mega(
    const float* __restrict__ dis, const uint16_t* __restrict__ mcatT,
    const float* __restrict__ alpha_p, const uint16_t* __restrict__ sigq,
    const uint16_t* __restrict__ woT, const float* __restrict__ x,
    const float* __restrict__ g_post,
    float* __restrict__ out1, uint16_t* __restrict__ h2) {
    __shared__ __align__(16) char sm[42496];
    uint16_t* Al = (uint16_t*)sm;            // 32 x 72 bf16   (4608 B)
    uint16_t* Bl = (uint16_t*)(sm + 4608);   // 256 x 72 bf16  (36864 B)
    float*    P  = (float*)sm;               // 32 x 264 f32   (33792 B) [epilogue]
    uint16_t* Att= (uint16_t*)(sm + 33792);  // 32 x 136 bf16  (8704 B)  [epilogue]
    __shared__ float rowsum[32];

    const int t = threadIdx.x;
    const int j0 = blockIdx.x * 32;
    const int b  = blockIdx.y;
    const float c = -12.0f * alpha_p[0];     // log2(4096)=12
    const int w = t >> 6, l = t & 63, ml = l & 15, qd = l >> 4;
    const bool aload = (t < 128);
    const int sj4 = (t & 7) * 4, si0 = ((t >> 3) & 15) * 4;
    const float* disb = dis + (size_t)b * 4096 * 4096 + j0;
    const uint16_t* mb = mcatT + (size_t)b * 256 * 4096;

    f32x4 acc[2][2];
    f32x4 zv = {0.f, 0.f, 0.f, 0.f};
    acc[0][0] = zv; acc[0][1] = zv; acc[1][0] = zv; acc[1][1] = zv;

    float dv[4][4];
    uint4 mc[4];
    // prefetch ks = 0
    if (aload) {
        #pragma unroll
        for (int r = 0; r < 4; ++r) {
            float4 v = *(const float4*)(disb + (size_t)(si0 + r) * 4096 + sj4);
            dv[r][0] = v.x; dv[r][1] = v.y; dv[r][2] = v.z; dv[r][3] = v.w;
        }
    }
    #pragma unroll
    for (int ii = 0; ii < 4; ++ii) {
        int idx = t + ii * 512;
        int row = idx >> 3, c8 = (idx & 7) * 8;
        mc[ii] = *(const uint4*)(mb + (size_t)row * 4096 + c8);
    }

    for (int ks = 0; ks < 64; ++ks) {
        __syncthreads();                 // previous MFMA done; LDS writable
        if (aload) {
            #pragma unroll
            for (int jj = 0; jj < 4; ++jj) {   // transpose 4x4 micro-block
                uint32_t lo = (uint32_t)f2bf(__expf(c * dv[0][jj])) |
                              ((uint32_t)f2bf(__expf(c * dv[1][jj])) << 16);
                uint32_t hi = (uint32_t)f2bf(__expf(c * dv[2][jj])) |
                              ((uint32_t)f2bf(__expf(c * dv[3][jj])) << 16);
                uint2 pk = {lo, hi};
                *(uint2*)&Al[(sj4 + jj) * 72 + si0] = pk;
            }
        }
        #pragma unroll
        for (int ii = 0; ii < 4; ++ii) {
            int idx = t + ii * 512;
            int row = idx >> 3, c8 = (idx & 7) * 8;
            *(uint4*)&Bl[row * 72 + c8] = mc[ii];
        }
        __syncthreads();
        if (ks < 63) {                   // issue next K-step's loads now;
            const int ig = (ks + 1) * 64;//   latency hides under MFMA below
            if (aload) {
                #pragma unroll
                for (int r = 0; r < 4; ++r) {
                    float4 v = *(const float4*)(disb + (size_t)(ig + si0 + r) * 4096 + sj4);
                    dv[r][0] = v.x; dv[r][1] = v.y; dv[r][2] = v.z; dv[r][3] = v.w;
                }
            }
            #pragma unroll
            for (int ii = 0; ii < 4; ++ii) {
                int idx = t + ii * 512;
                int row = idx >> 3, c8 = (idx & 7) * 8;
                mc[ii] = *(const uint4*)(mb + (size_t)row * 4096 + ig + c8);
            }
        }
        #pragma unroll
        for (int kc = 0; kc < 2; ++kc) {
            short8 af0 = *(const short8*)&Al[(ml) * 72 + kc * 32 + qd * 8];
            short8 af1 = *(const short8*)&Al[(16 + ml) * 72 + kc * 32 + qd * 8];
            short8 bf0 = *(const short8*)&Bl[(w * 32 + ml) * 72 + kc * 32 + qd * 8];
            short8 bf1 = *(const short8*)&Bl[(w * 32 + 16 + ml) * 72 + kc * 32 + qd * 8];
            acc[0][0] = mfma16(af0, bf0, acc[0][0]);
            acc[0][1] = mfma16(af0, bf1, acc[0][1]);
            acc[1][0] = mfma16(af1, bf0, acc[1][0]);
            acc[1][1] = mfma16(af1, bf1, acc[1][1]);
        }
    }

    // ---- epilogue: merge w1/w2, att@Wo, residual, rmsnorm ----
    __syncthreads();
    {
        const int colb = w * 32;
        #pragma unroll
        for (int fm = 0; fm < 2; ++fm)
            #pragma unroll
            for (int fn = 0; fn < 2; ++fn) {
                int col = colb + fn * 16 + ml;
                #pragma unroll
                for (int r = 0; r < 4; ++r)
                    P[(fm * 16 + qd * 4 + r) * 264 + col] = acc[fm][fn][r];
            }
    }
    if (t < 32) rowsum[t] = 0.f;
    __syncthreads();
    {
        const uint16_t* sq = sigq + (size_t)(b * 4096 + j0) * 128;
        #pragma unroll
        for (int it = 0; it < 2; ++it) {
            int q = t + it * 512;
            int j = q >> 5, c4 = (q & 31) * 4;
            float4 w1v = *(const float4*)&P[j * 264 + c4];
            float4 w2v = *(const float4*)&P[j * 264 + 128 + c4];
            const uint16_t* sp = sq + j * 128 + c4;
            uint32_t lo = (uint32_t)f2bf(bf2f(sp[0]) * w1v.x / w2v.x) |
                          ((uint32_t)f2bf(bf2f(sp[1]) * w1v.y / w2v.y) << 16);
            uint32_t hi = (uint32_t)f2bf(bf2f(sp[2]) * w1v.z / w2v.z) |
                          ((uint32_t)f2bf(bf2f(sp[3]) * w1v.w / w2v.w) << 16);
            uint2 pk = {lo, hi};
            *(uint2*)&Att[j * 136 + c4] = pk;
        }
    }
    __syncthreads();
    f32x4 acc2[2];
    acc2[0] = zv; acc2[1] = zv;
    #pragma unroll
    for (int kc = 0; kc < 4; ++kc) {
        short8 af0 = *(const short8*)&Att[(ml) * 136 + kc * 32 + qd * 8];
        short8 af1 = *(const short8*)&Att[(16 + ml) * 136 + kc * 32 + qd * 8];
        short8 bf  = *(const short8*)(woT + (w * 16 + ml) * 128 + kc * 32 + qd * 8);
        acc2[0] = mfma16(af0, bf, acc2[0]);
        acc2[1] = mfma16(af1, bf, acc2[1]);
    }
    const int col = w * 16 + ml;
    const float gp = g_post[col];
    float ov[2][4];
    #pragma unroll
    for (int fm = 0; fm < 2; ++fm)
        #pragma unroll
        for (int r = 0; r < 4; ++r) {
            int rowl = fm * 16 + qd * 4 + r;
            size_t o = (size_t)(b * 4096 + j0 + rowl) * 128 + col;
            float v = x[o] + acc2[fm][r];
            ov[fm][r] = v;
            out1[o] = v;
            float ss = v * v;              // reduce over the 16 ml lanes (cols)
            ss += __shfl_xor(ss, 1, 64);
            ss += __shfl_xor(ss, 2, 64);
            ss += __shfl_xor(ss, 4, 64);
            ss += __shfl_xor(ss, 8, 64);
            if (ml == 0) atomicAdd(&rowsum[rowl], ss);
        }
    __syncthreads();
    #pragma unroll
    for (int fm = 0; fm < 2; ++fm)
        #pragma unroll
        for (int r = 0; r < 4; ++r) {
            int rowl = fm * 16 + qd * 4 + r;
            float rs = rsqrtf(rowsum[rowl] * (1.f / 128.f) + 1e-6f);
            h2[(size_t)(b * 4096 + j0 + rowl) * 128 + col] = f2bf(ov[fm][r] * rs * gp);
        }
}

// ---------------------------------------------------------------- k_ff
// Fused FFN: R = relu(h2 @ W1 + b1) kept in LDS (two 256-col halves),
// out = out1 + R @ W2 + b2. One block per 64 rows, 8 waves.
__global__ __launch_bounds__(512) void k_ff(
    const uint16_t* __restrict__ h2, const uint16_t* __restrict__ w1T,
    const float* __restrict__ b1, const uint16_t* __restrict__ w2T,
    const float* __restrict__ b2, const float* __restrict__ out1,
    float* __restrict__ out) {
    __shared__ __align__(16) uint16_t Al[64 * 136];   // 17408 B
    __shared__ __align__(16) uint16_t Rl[64 * 264];   // 33792 B
    const int t = threadIdx.x;
    const int i0 = blockIdx.x * 64;
    const int w = t >> 6, l = t & 63, ml = l & 15, qd = l >> 4;
    #pragma unroll
    for (int ii = 0; ii < 2; ++ii) {
        int idx = t + ii * 512;
        int row = idx >> 4, c8 = (idx & 15) * 8;
        *(uint4*)&Al[row * 136 + c8] =
            *(const uint4*)(h2 + (size_t)(i0 + row) * 128 + c8);
    }
    __syncthreads();
    const int wm = w >> 2, wn = w & 3;
    f32x4 zv = {0.f, 0.f, 0.f, 0.f};
    f32x4 a2[2][2];
    a2[0][0] = zv; a2[0][1] = zv; a2[1][0] = zv; a2[1][1] = zv;
    for (int hf = 0; hf < 2; ++hf) {
        if (hf) __syncthreads();           // phase-2 readers of Rl done
        // phase 1: R[:, hf*256 .. +256) = relu(h2 @ W1 + b1)
        f32x4 a1[4][2];
        #pragma unroll
        for (int fm = 0; fm < 4; ++fm) { a1[fm][0] = zv; a1[fm][1] = zv; }
        #pragma unroll
        for (int kc = 0; kc < 4; ++kc) {
            short8 af[4], bfr[2];
            #pragma unroll
            for (int fm = 0; fm < 4; ++fm)
                af[fm] = *(const short8*)&Al[(fm * 16 + ml) * 136 + kc * 32 + qd * 8];
            #pragma unroll
            for (int fn = 0; fn < 2; ++fn)
                bfr[fn] = *(const short8*)(w1T +
                    (size_t)(hf * 256 + w * 32 + fn * 16 + ml) * 128 + kc * 32 + qd * 8);
            #pragma unroll
            for (int fm = 0; fm < 4; ++fm)
                #pragma unroll
                for (int fn = 0; fn < 2; ++fn)
                    a1[fm][fn] = mfma16(af[fm], bfr[fn], a1[fm][fn]);
        }
        #pragma unroll
        for (int fm = 0; fm < 4; ++fm)
            #pragma unroll
            for (int fn = 0; fn < 2; ++fn) {
                int fcol = w * 32 + fn * 16 + ml;
                float bias = b1[hf * 256 + fcol];
                #pragma unroll
                for (int r = 0; r < 4; ++r) {
                    int row = fm * 16 + qd * 4 + r;
                    Rl[row * 264 + fcol] = f2bf(fmaxf(a1[fm][fn][r] + bias, 0.f));
                }
            }
        __syncthreads();
        // phase 2: accumulate R_half @ W2_half
        #pragma unroll
        for (int kc = 0; kc < 8; ++kc) {
            short8 af[2], bfr[2];
            #pragma unroll
            for (int fm = 0; fm < 2; ++fm)
                af[fm] = *(const short8*)&Rl[(wm * 32 + fm * 16 + ml) * 264 + kc * 32 + qd * 8];
            #pragma unroll
            for (int fn = 0; fn < 2; ++fn)
                bfr[fn] = *(const short8*)(w2T +
                    (size_t)(wn * 32 + fn * 16 + ml) * 512 + hf * 256 + kc * 32 + qd * 8);
            #pragma unroll
            for (int fm = 0; fm < 2; ++fm)
                #pragma unroll
                for (int fn = 0; fn < 2; ++fn)
                    a2[fm][fn] = mfma16(af[fm], bfr[fn], a2[fm][fn]);
        }
    }
    #pragma unroll
    for (int fm = 0; fm < 2; ++fm)
        #pragma unroll
        for (int fn = 0; fn < 2; ++fn) {
            int colo = wn * 32 + fn * 16 + ml;
            float bias = b2[colo];
            #pragma unroll
            for (int r = 0; r < 4; ++r) {
                int rowl = wm * 32 + fm * 16 + qd * 4 + r;
                size_t o = (size_t)(i0 + rowl) * 128 + colo;
                out[o] = out1[o] + bias + a2[fm][fn][r];
            }
        }
}

// ---------------------------------------------------------------- launch
extern "C" void kernel_launch(void* const* d_in, const int* in_sizes, int n_in,
                              void* d_out, int out_size, void* d_ws, size_t ws_size,
                              hipStream_t stream) {
    (void)in_sizes; (void)n_in; (void)out_size; (void)ws_size;
    const float* x      = (const float*)d_in[0];
    const float* dis    = (const float*)d_in[1];
    const float* g_in   = (const float*)d_in[2];
    const float* g_post = (const float*)d_in[3];
    const float* Wq     = (const float*)d_in[4];
    const float* Wk     = (const float*)d_in[5];
    const float* Wv     = (const float*)d_in[6];
    const float* alpha  = (const float*)d_in[7];
    const float* Wo     = (const float*)d_in[8];
    const float* W1     = (const float*)d_in[9];
    const float* b1     = (const float*)d_in[10];
    const float* W2     = (const float*)d_in[11];
    const float* b2     = (const float*)d_in[12];
    float* out = (float*)d_out;

    char* ws = (char*)d_ws;
    size_t off = 0;
    auto take = [&](size_t bytes) -> char* {
        char* p = ws + off;
        off += (bytes + 255) & ~(size_t)255;
        return p;
    };
    uint16_t* h     = (uint16_t*)take(16384ull * 128 * 2);     //  4 MB
    uint16_t* wqkvT = (uint16_t*)take(384ull * 128 * 2);
    uint16_t* woT   = (uint16_t*)take(128ull * 128 * 2);
    uint16_t* w1T   = (uint16_t*)take(512ull * 128 * 2);
    uint16_t* w2T   = (uint16_t*)take(128ull * 512 * 2);
    uint16_t* sigq  = (uint16_t*)take(16384ull * 128 * 2);     //  4 MB
    uint16_t* mcatT = (uint16_t*)take(4ull * 256 * 4096 * 2);  //  8 MB
    float*    out1  = (float*)take(16384ull * 128 * 4);        //  8 MB
    uint16_t* h2    = (uint16_t*)take(16384ull * 128 * 2);     //  4 MB

    k_prep<<<768, 256, 0, stream>>>(Wq, Wk, Wv, Wo, W1, W2, wqkvT, woT, w1T, w2T);
    k_rms<<<4096, 256, 0, stream>>>(x, g_in, h);
    k_qkv<<<256, 384, 0, stream>>>(h, wqkvT, sigq, mcatT);
    k_mega<<<dim3(128, 4), 512, 0, stream>>>(dis, mcatT, alpha, sigq, woT, x, g_post, out1, h2);
    k_ff<<<256, 512, 0, stream>>>(h2, w1T, b1, w2T, b2, out1, out);
}

// Round 2
// 500.298 us; speedup vs baseline: 1.3977x; 1.3977x over previous
//
#include <hip/hip_runtime.h>
#include <stdint.h>

// Problem constants: B=4, N=4096, E=128, H=8, D=16, FF=512
// Heads never mix across the E axis -> treat everything as [B*N, 128].

typedef __attribute__((ext_vector_type(8))) short short8;   // 8 bf16 (4 VGPRs)
typedef __attribute__((ext_vector_type(4))) float f32x4;

__device__ __forceinline__ uint16_t f2bf(float f) {
    uint32_t u = __builtin_bit_cast(uint32_t, f);
    u += 0x7fffu + ((u >> 16) & 1u);   // RNE
    return (uint16_t)(u >> 16);
}
__device__ __forceinline__ float bf2f(uint16_t h) {
    uint32_t u = ((uint32_t)h) << 16;
    return __builtin_bit_cast(float, u);
}
__device__ __forceinline__ f32x4 mfma16(short8 a, short8 b, f32x4 c) {
    return __builtin_amdgcn_mfma_f32_16x16x32_bf16(a, b, c, 0, 0, 0);
}

// ---------------------------------------------------------------- k_prep
__global__ __launch_bounds__(256) void k_prep(
    const float* __restrict__ Wq, const float* __restrict__ Wk,
    const float* __restrict__ Wv, const float* __restrict__ Wo,
    const float* __restrict__ W1, const float* __restrict__ W2,
    uint16_t* __restrict__ wqkvT, uint16_t* __restrict__ woT,
    uint16_t* __restrict__ w1T, uint16_t* __restrict__ w2T) {
    int t = blockIdx.x * 256 + threadIdx.x;
    if (t < 49152) {                       // wqkvT[n][k], n in [0,384)
        int n = t >> 7, k = t & 127;
        const float* W = (n < 128) ? Wq : (n < 256) ? Wk : Wv;
        wqkvT[t] = f2bf(W[k * 128 + (n & 127)]);
    } else if (t < 65536) {                // woT[e][d] = Wo[d][e]
        int i = t - 49152; int e = i >> 7, d = i & 127;
        woT[i] = f2bf(Wo[d * 128 + e]);
    } else if (t < 131072) {               // w1T[f][e] = W1[e][f]
        int i = t - 65536; int f = i >> 7, e = i & 127;
        w1T[i] = f2bf(W1[e * 512 + f]);
    } else if (t < 196608) {               // w2T[e][f] = W2[f][e]
        int i = t - 131072; int e = i >> 9, f = i & 511;
        w2T[i] = f2bf(W2[f * 128 + e]);
    }
}

// ---------------------------------------------------------------- k_rms
__global__ __launch_bounds__(256) void k_rms(
    const float* __restrict__ x, const float* __restrict__ g,
    uint16_t* __restrict__ o) {
    int row = blockIdx.x * 4 + (threadIdx.x >> 6);
    int l = threadIdx.x & 63;
    float2 v = *(const float2*)(x + (size_t)row * 128 + l * 2);
    float ss = v.x * v.x + v.y * v.y;
    #pragma unroll
    for (int m = 32; m >= 1; m >>= 1) ss += __shfl_xor(ss, m, 64);
    float rs = rsqrtf(ss * (1.0f / 128.0f) + 1e-6f);
    float2 gv = *(const float2*)(g + l * 2);
    uint32_t lo = (uint32_t)f2bf(v.x * rs * gv.x) |
                  ((uint32_t)f2bf(v.y * rs * gv.y) << 16);
    *(uint32_t*)(o + (size_t)row * 128 + l * 2) = lo;
}

// ---------------------------------------------------------------- k_qkv
// [64 x 128] h-tile @ [128 x 384] Wqkv. 6 waves, each 64x64.
// Epilogue: sigq = sigmoid(q) (bf16), McatT[b][col][i] = [exp(k)*v | exp(k)].
__global__ __launch_bounds__(384) void k_qkv(
    const uint16_t* __restrict__ h, const uint16_t* __restrict__ wqkvT,
    uint16_t* __restrict__ sigq, uint16_t* __restrict__ mcatT) {
    __shared__ __align__(16) char sm[65536];
    uint16_t* Al = (uint16_t*)sm;   // 64 x 136 bf16
    float*    Pl = (float*)sm;      // 64 x 256 f32, after K-loop
    const int t = threadIdx.x;
    const int i0 = blockIdx.x * 64;
    for (int idx = t; idx < 1024; idx += 384) {
        int row = idx >> 4, c8 = (idx & 15) * 8;
        *(uint4*)&Al[row * 136 + c8] =
            *(const uint4*)(h + (size_t)(i0 + row) * 128 + c8);
    }
    __syncthreads();
    const int w = t >> 6, l = t & 63, ml = l & 15, qd = l >> 4;
    f32x4 acc[4][4];
    f32x4 zv = {0.f, 0.f, 0.f, 0.f};
    #pragma unroll
    for (int a = 0; a < 4; ++a)
        #pragma unroll
        for (int b = 0; b < 4; ++b) acc[a][b] = zv;
    #pragma unroll
    for (int kc = 0; kc < 4; ++kc) {
        short8 af[4], bfr[4];
        #pragma unroll
        for (int fm = 0; fm < 4; ++fm)
            af[fm] = *(const short8*)&Al[(fm * 16 + ml) * 136 + kc * 32 + qd * 8];
        #pragma unroll
        for (int fn = 0; fn < 4; ++fn)
            bfr[fn] = *(const short8*)(wqkvT + (w * 64 + fn * 16 + ml) * 128 + kc * 32 + qd * 8);
        #pragma unroll
        for (int fm = 0; fm < 4; ++fm)
            #pragma unroll
            for (int fn = 0; fn < 4; ++fn)
                acc[fm][fn] = mfma16(af[fm], bfr[fn], acc[fm][fn]);
    }
    __syncthreads();
    const int bb = i0 >> 12, il0 = i0 & 4095;
    if (w < 2) {       // q columns -> sigmoid, straight to global
        #pragma unroll
        for (int fm = 0; fm < 4; ++fm)
            #pragma unroll
            for (int fn = 0; fn < 4; ++fn)
                #pragma unroll
                for (int r = 0; r < 4; ++r) {
                    int row = fm * 16 + qd * 4 + r;
                    int col = w * 64 + fn * 16 + ml;
                    sigq[(size_t)(i0 + row) * 128 + col] =
                        f2bf(1.f / (1.f + __expf(-acc[fm][fn][r])));
                }
    } else {           // k -> exp(k) at Pl cols [0,128); v raw at [128,256)
        int half = (w < 4) ? 0 : 1;
        int cbase = (w - (half ? 4 : 2)) * 64;
        #pragma unroll
        for (int fm = 0; fm < 4; ++fm)
            #pragma unroll
            for (int fn = 0; fn < 4; ++fn)
                #pragma unroll
                for (int r = 0; r < 4; ++r) {
                    int row = fm * 16 + qd * 4 + r;
                    int col = cbase + fn * 16 + ml;
                    float vv = acc[fm][fn][r];
                    if (!half) vv = __expf(vv);
                    Pl[row * 256 + half * 128 + ((col + row) & 127)] = vv;
                }
    }
    __syncthreads();
    for (int idx = t; idx < 16384; idx += 384) {
        int cc = idx >> 6, il = idx & 63;
        int pc = ((cc & 127) + il) & 127;
        float ekw = Pl[il * 256 + pc];
        float val = (cc < 128) ? ekw * Pl[il * 256 + 128 + pc] : ekw;
        mcatT[((size_t)bb * 256 + cc) * 4096 + il0 + il] = f2bf(val);
    }
}

// ---------------------------------------------------------------- k_mega
// Fuses k_big + k_att + rmsnorm2. Per (j-tile of 32, batch):
//   P[32 x 256] = sum_i exp(c*dis[i][j]) * Mcat[i][col]   (full K=4096)
//   att = sigq * (P[:, :128] / P[:, 128:])                (bf16)
//   out1 = x + att @ Wo ; h2 = rmsnorm(out1, g_post)
// Spill-safe redesign: B-frags straight from L2 (mcat = 2 MB/batch, resident),
// dis prefetch = ONE named float4 per thread (dvA/dvB, 2-step unrolled loop),
// Al double-buffered -> exactly one __syncthreads per K-step.
__global__ __launch_bounds__(512) void k_mega(
    const float* __restrict__ dis, const uint16_t* __restrict__ mcatT,
    const float* __restrict__ alpha_p, const uint16_t* __restrict__ sigq,
    const uint16_t* __restrict__ woT, const float* __restrict__ x,
    const float* __restrict__ g_post,
    float* __restrict__ out1, uint16_t* __restrict__ h2) {
    __shared__ __align__(16) char sm[42496];
    uint16_t* Al0 = (uint16_t*)sm;           // 32 x 72 bf16 (4608 B)
    uint16_t* Al1 = (uint16_t*)(sm + 4608);  // 32 x 72 bf16 (4608 B)
    float*    P   = (float*)sm;              // 32 x 264 f32 (33792 B) [epilogue]
    uint16_t* Att = (uint16_t*)(sm + 33792); // 32 x 136 bf16 (8704 B) [epilogue]
    __shared__ float rowsum[32];

    const int t = threadIdx.x;
    const int j0 = blockIdx.x * 32;
    const int b  = blockIdx.y;
    const float c = -12.0f * alpha_p[0];     // log2(4096)=12
    const int w = t >> 6, l = t & 63, ml = l & 15, qd = l >> 4;
    const int il = t >> 3;                   // i-row 0..63 within K-step
    const int j4 = (t & 7) * 4;              // j column group
    const float* disb = dis + (size_t)b * 4096 * 4096 + j0;
    const uint16_t* mb = mcatT + (size_t)b * 256 * 4096;
    const int brow0 = (w * 32 + ml) * 4096;        // B row for bf0
    const int brow1 = (w * 32 + 16 + ml) * 4096;   // B row for bf1

    f32x4 acc00, acc01, acc10, acc11;
    f32x4 zv = {0.f, 0.f, 0.f, 0.f};
    acc00 = zv; acc01 = zv; acc10 = zv; acc11 = zv;

    // prologue: Al0 <- step 0, dvB <- step 1 (in flight)
    float4 dvP = *(const float4*)(disb + (size_t)il * 4096 + j4);
    Al0[(j4 + 0) * 72 + il] = f2bf(__expf(c * dvP.x));
    Al0[(j4 + 1) * 72 + il] = f2bf(__expf(c * dvP.y));
    Al0[(j4 + 2) * 72 + il] = f2bf(__expf(c * dvP.z));
    Al0[(j4 + 3) * 72 + il] = f2bf(__expf(c * dvP.w));
    float4 dvB = *(const float4*)(disb + (size_t)(64 + il) * 4096 + j4);
    __syncthreads();

    for (int m = 0; m < 32; ++m) {
        const bool pf = (m < 31);
        // ---------------- even step t = 2m : MFMA from Al0 ----------------
        float4 dvA;
        if (pf) dvA = *(const float4*)(disb + (size_t)((2 * m + 2) * 64 + il) * 4096 + j4);
        {
            const int ig = 2 * m * 64;
            #pragma unroll
            for (int kc = 0; kc < 2; ++kc) {
                short8 af0 = *(const short8*)&Al0[ml * 72 + kc * 32 + qd * 8];
                short8 af1 = *(const short8*)&Al0[(16 + ml) * 72 + kc * 32 + qd * 8];
                short8 bf0 = *(const short8*)(mb + brow0 + ig + kc * 32 + qd * 8);
                short8 bf1 = *(const short8*)(mb + brow1 + ig + kc * 32 + qd * 8);
                acc00 = mfma16(af0, bf0, acc00);
                acc01 = mfma16(af0, bf1, acc01);
                acc10 = mfma16(af1, bf0, acc10);
                acc11 = mfma16(af1, bf1, acc11);
            }
        }
        // write Al1 <- dis(2m+1) held in dvB (loaded one full step ago)
        Al1[(j4 + 0) * 72 + il] = f2bf(__expf(c * dvB.x));
        Al1[(j4 + 1) * 72 + il] = f2bf(__expf(c * dvB.y));
        Al1[(j4 + 2) * 72 + il] = f2bf(__expf(c * dvB.z));
        Al1[(j4 + 3) * 72 + il] = f2bf(__expf(c * dvB.w));
        __syncthreads();
        // ---------------- odd step t = 2m+1 : MFMA from Al1 ----------------
        if (pf) dvB = *(const float4*)(disb + (size_t)((2 * m + 3) * 64 + il) * 4096 + j4);
        {
            const int ig = (2 * m + 1) * 64;
            #pragma unroll
            for (int kc = 0; kc < 2; ++kc) {
                short8 af0 = *(const short8*)&Al1[ml * 72 + kc * 32 + qd * 8];
                short8 af1 = *(const short8*)&Al1[(16 + ml) * 72 + kc * 32 + qd * 8];
                short8 bf0 = *(const short8*)(mb + brow0 + ig + kc * 32 + qd * 8);
                short8 bf1 = *(const short8*)(mb + brow1 + ig + kc * 32 + qd * 8);
                acc00 = mfma16(af0, bf0, acc00);
                acc01 = mfma16(af0, bf1, acc01);
                acc10 = mfma16(af1, bf0, acc10);
                acc11 = mfma16(af1, bf1, acc11);
            }
        }
        if (pf) {      // write Al0 <- dis(2m+2) held in dvA
            Al0[(j4 + 0) * 72 + il] = f2bf(__expf(c * dvA.x));
            Al0[(j4 + 1) * 72 + il] = f2bf(__expf(c * dvA.y));
            Al0[(j4 + 2) * 72 + il] = f2bf(__expf(c * dvA.z));
            Al0[(j4 + 3) * 72 + il] = f2bf(__expf(c * dvA.w));
        }
        __syncthreads();
    }

    // ---- epilogue: merge w1/w2, att@Wo, residual, rmsnorm ----
    {
        const int colb = w * 32;
        #pragma unroll
        for (int r = 0; r < 4; ++r) {
            P[(qd * 4 + r) * 264 + colb + ml] = acc00[r];
            P[(qd * 4 + r) * 264 + colb + 16 + ml] = acc01[r];
            P[(16 + qd * 4 + r) * 264 + colb + ml] = acc10[r];
            P[(16 + qd * 4 + r) * 264 + colb + 16 + ml] = acc11[r];
        }
    }
    if (t < 32) rowsum[t] = 0.f;
    __syncthreads();
    {
        const uint16_t* sq = sigq + (size_t)(b * 4096 + j0) * 128;
        #pragma unroll
        for (int it = 0; it < 2; ++it) {
            int q = t + it * 512;
            int j = q >> 5, c4 = (q & 31) * 4;
            float4 w1v = *(const float4*)&P[j * 264 + c4];
            float4 w2v = *(const float4*)&P[j * 264 + 128 + c4];
            const uint16_t* sp = sq + j * 128 + c4;
            uint32_t lo = (uint32_t)f2bf(bf2f(sp[0]) * w1v.x / w2v.x) |
                          ((uint32_t)f2bf(bf2f(sp[1]) * w1v.y / w2v.y) << 16);
            uint32_t hi = (uint32_t)f2bf(bf2f(sp[2]) * w1v.z / w2v.z) |
                          ((uint32_t)f2bf(bf2f(sp[3]) * w1v.w / w2v.w) << 16);
            uint2 pk = {lo, hi};
            *(uint2*)&Att[j * 136 + c4] = pk;
        }
    }
    __syncthreads();
    f32x4 acc2a = zv, acc2b = zv;
    #pragma unroll
    for (int kc = 0; kc < 4; ++kc) {
        short8 af0 = *(const short8*)&Att[ml * 136 + kc * 32 + qd * 8];
        short8 af1 = *(const short8*)&Att[(16 + ml) * 136 + kc * 32 + qd * 8];
        short8 bf  = *(const short8*)(woT + (w * 16 + ml) * 128 + kc * 32 + qd * 8);
        acc2a = mfma16(af0, bf, acc2a);
        acc2b = mfma16(af1, bf, acc2b);
    }
    const int col = w * 16 + ml;
    const float gp = g_post[col];
    float ov0[4], ov1[4];
    #pragma unroll
    for (int r = 0; r < 4; ++r) {
        int rowl = qd * 4 + r;
        size_t o = (size_t)(b * 4096 + j0 + rowl) * 128 + col;
        float v = x[o] + acc2a[r];
        ov0[r] = v;
        out1[o] = v;
        float ss = v * v;
        ss += __shfl_xor(ss, 1, 64);
        ss += __shfl_xor(ss, 2, 64);
        ss += __shfl_xor(ss, 4, 64);
        ss += __shfl_xor(ss, 8, 64);
        if (ml == 0) atomicAdd(&rowsum[rowl], ss);
    }
    #pragma unroll
    for (int r = 0; r < 4; ++r) {
        int rowl = 16 + qd * 4 + r;
        size_t o = (size_t)(b * 4096 + j0 + rowl) * 128 + col;
        float v = x[o] + acc2b[r];
        ov1[r] = v;
        out1[o] = v;
        float ss = v * v;
        ss += __shfl_xor(ss, 1, 64);
        ss += __shfl_xor(ss, 2, 64);
        ss += __shfl_xor(ss, 4, 64);
        ss += __shfl_xor(ss, 8, 64);
        if (ml == 0) atomicAdd(&rowsum[rowl], ss);
    }
    __syncthreads();
    #pragma unroll
    for (int r = 0; r < 4; ++r) {
        int rowl = qd * 4 + r;
        float rs = rsqrtf(rowsum[rowl] * (1.f / 128.f) + 1e-6f);
        h2[(size_t)(b * 4096 + j0 + rowl) * 128 + col] = f2bf(ov0[r] * rs * gp);
    }
    #pragma unroll
    for (int r = 0; r < 4; ++r) {
        int rowl = 16 + qd * 4 + r;
        float rs = rsqrtf(rowsum[rowl] * (1.f / 128.f) + 1e-6f);
        h2[(size_t)(b * 4096 + j0 + rowl) * 128 + col] = f2bf(ov1[r] * rs * gp);
    }
}

// ---------------------------------------------------------------- k_ff
// Fused FFN: R = relu(h2 @ W1 + b1) kept in LDS (two 256-col halves),
// out = out1 + R @ W2 + b2. One block per 64 rows, 8 waves.
__global__ __launch_bounds__(512) void k_ff(
    const uint16_t* __restrict__ h2, const uint16_t* __restrict__ w1T,
    const float* __restrict__ b1, const uint16_t* __restrict__ w2T,
    const float* __restrict__ b2, const float* __restrict__ out1,
    float* __restrict__ out) {
    __shared__ __align__(16) uint16_t Al[64 * 136];   // 17408 B
    __shared__ __align__(16) uint16_t Rl[64 * 264];   // 33792 B
    const int t = threadIdx.x;
    const int i0 = blockIdx.x * 64;
    const int w = t >> 6, l = t & 63, ml = l & 15, qd = l >> 4;
    #pragma unroll
    for (int ii = 0; ii < 2; ++ii) {
        int idx = t + ii * 512;
        int row = idx >> 4, c8 = (idx & 15) * 8;
        *(uint4*)&Al[row * 136 + c8] =
            *(const uint4*)(h2 + (size_t)(i0 + row) * 128 + c8);
    }
    __syncthreads();
    const int wm = w >> 2, wn = w & 3;
    f32x4 zv = {0.f, 0.f, 0.f, 0.f};
    f32x4 a2[2][2];
    a2[0][0] = zv; a2[0][1] = zv; a2[1][0] = zv; a2[1][1] = zv;
    for (int hf = 0; hf < 2; ++hf) {
        if (hf) __syncthreads();           // phase-2 readers of Rl done
        // phase 1: R[:, hf*256 .. +256) = relu(h2 @ W1 + b1)
        f32x4 a1[4][2];
        #pragma unroll
        for (int fm = 0; fm < 4; ++fm) { a1[fm][0] = zv; a1[fm][1] = zv; }
        #pragma unroll
        for (int kc = 0; kc < 4; ++kc) {
            short8 af[4], bfr[2];
            #pragma unroll
            for (int fm = 0; fm < 4; ++fm)
                af[fm] = *(const short8*)&Al[(fm * 16 + ml) * 136 + kc * 32 + qd * 8];
            #pragma unroll
            for (int fn = 0; fn < 2; ++fn)
                bfr[fn] = *(const short8*)(w1T +
                    (size_t)(hf * 256 + w * 32 + fn * 16 + ml) * 128 + kc * 32 + qd * 8);
            #pragma unroll
            for (int fm = 0; fm < 4; ++fm)
                #pragma unroll
                for (int fn = 0; fn < 2; ++fn)
                    a1[fm][fn] = mfma16(af[fm], bfr[fn], a1[fm][fn]);
        }
        #pragma unroll
        for (int fm = 0; fm < 4; ++fm)
            #pragma unroll
            for (int fn = 0; fn < 2; ++fn) {
                int fcol = w * 32 + fn * 16 + ml;
                float bias = b1[hf * 256 + fcol];
                #pragma unroll
                for (int r = 0; r < 4; ++r) {
                    int row = fm * 16 + qd * 4 + r;
                    Rl[row * 264 + fcol] = f2bf(fmaxf(a1[fm][fn][r] + bias, 0.f));
                }
            }
        __syncthreads();
        // phase 2: accumulate R_half @ W2_half
        #pragma unroll
        for (int kc = 0; kc < 8; ++kc) {
            short8 af[2], bfr[2];
            #pragma unroll
            for (int fm = 0; fm < 2; ++fm)
                af[fm] = *(const short8*)&Rl[(wm * 32 + fm * 16 + ml) * 264 + kc * 32 + qd * 8];
            #pragma unroll
            for (int fn = 0; fn < 2; ++fn)
                bfr[fn] = *(const short8*)(w2T +
                    (size_t)(wn * 32 + fn * 16 + ml) * 512 + hf * 256 + kc * 32 + qd * 8);
            #pragma unroll
            for (int fm = 0; fm < 2; ++fm)
                #pragma unroll
                for (int fn = 0; fn < 2; ++fn)
                    a2[fm][fn] = mfma16(af[fm], bfr[fn], a2[fm][fn]);
        }
    }
    #pragma unroll
    for (int fm = 0; fm < 2; ++fm)
        #pragma unroll
        for (int fn = 0; fn < 2; ++fn) {
            int colo = wn * 32 + fn * 16 + ml;
            float bias = b2[colo];
            #pragma unroll
            for (int r = 0; r < 4; ++r) {
                int rowl = wm * 32 + fm * 16 + qd * 4 + r;
                size_t o = (size_t)(i0 + rowl) * 128 + colo;
                out[o] = out1[o] + bias + a2[fm][fn][r];
            }
        }
}

// ---------------------------------------------------------------- launch
extern "C" void kernel_launch(void* const* d_in, const int* in_sizes, int n_in,
                              void* d_out, int out_size, void* d_ws, size_t ws_size,
                              hipStream_t stream) {
    (void)in_sizes; (void)n_in; (void)out_size; (void)ws_size;
    const float* x      = (const float*)d_in[0];
    const float* dis    = (const float*)d_in[1];
    const float* g_in   = (const float*)d_in[2];
    const float* g_post = (const float*)d_in[3];
    const float* Wq     = (const float*)d_in[4];
    const float* Wk     = (const float*)d_in[5];
    const float* Wv     = (const float*)d_in[6];
    const float* alpha  = (const float*)d_in[7];
    const float* Wo     = (const float*)d_in[8];
    const float* W1     = (const float*)d_in[9];
    const float* b1     = (const float*)d_in[10];
    const float* W2     = (const float*)d_in[11];
    const float* b2     = (const float*)d_in[12];
    float* out = (float*)d_out;

    char* ws = (char*)d_ws;
    size_t off = 0;
    auto take = [&](size_t bytes) -> char* {
        char* p = ws + off;
        off += (bytes + 255) & ~(size_t)255;
        return p;
    };
    uint16_t* h     = (uint16_t*)take(16384ull * 128 * 2);     //  4 MB
    uint16_t* wqkvT = (uint16_t*)take(384ull * 128 * 2);
    uint16_t* woT   = (uint16_t*)take(128ull * 128 * 2);
    uint16_t* w1T   = (uint16_t*)take(512ull * 128 * 2);
    uint16_t* w2T   = (uint16_t*)take(128ull * 512 * 2);
    uint16_t* sigq  = (uint16_t*)take(16384ull * 128 * 2);     //  4 MB
    uint16_t* mcatT = (uint16_t*)take(4ull * 256 * 4096 * 2);  //  8 MB
    float*    out1  = (float*)take(16384ull * 128 * 4);        //  8 MB
    uint16_t* h2    = (uint16_t*)take(16384ull * 128 * 2);     //  4 MB

    k_prep<<<768, 256, 0, stream>>>(Wq, Wk, Wv, Wo, W1, W2, wqkvT, woT, w1T, w2T);
    k_rms<<<4096, 256, 0, stream>>>(x, g_in, h);
    k_qkv<<<256, 384, 0, stream>>>(h, wqkvT, sigq, mcatT);
    k_mega<<<dim3(128, 4), 512, 0, stream>>>(dis, mcatT, alpha, sigq, woT, x, g_post, out1, h2);
    k_ff<<<256, 512, 0, stream>>>(h2, w1T, b1, w2T, b2, out1, out);
}

// Round 3
// 494.484 us; speedup vs baseline: 1.4141x; 1.0118x over previous
//
#include <hip/hip_runtime.h>
#include <stdint.h>

// Problem constants: B=4, N=4096, E=128, H=8, D=16, FF=512
// Heads never mix across the E axis -> treat everything as [B*N, 128].

typedef __attribute__((ext_vector_type(8))) short short8;   // 8 bf16 (4 VGPRs)
typedef __attribute__((ext_vector_type(4))) float f32x4;

__device__ __forceinline__ uint16_t f2bf(float f) {
    uint32_t u = __builtin_bit_cast(uint32_t, f);
    u += 0x7fffu + ((u >> 16) & 1u);   // RNE
    return (uint16_t)(u >> 16);
}
__device__ __forceinline__ float bf2f(uint16_t h) {
    uint32_t u = ((uint32_t)h) << 16;
    return __builtin_bit_cast(float, u);
}
__device__ __forceinline__ f32x4 mfma16(short8 a, short8 b, f32x4 c) {
    return __builtin_amdgcn_mfma_f32_16x16x32_bf16(a, b, c, 0, 0, 0);
}
// Barrier that makes LDS traffic visible but leaves global loads IN FLIGHT
// (T4: __syncthreads would drain vmcnt(0) and kill the dis/mcat prefetch).
__device__ __forceinline__ void barrier_lgkm() {
    asm volatile("s_waitcnt lgkmcnt(0)" ::: "memory");
    __builtin_amdgcn_s_barrier();
}

// ---------------------------------------------------------------- k_prep
__global__ __launch_bounds__(256) void k_prep(
    const float* __restrict__ Wq, const float* __restrict__ Wk,
    const float* __restrict__ Wv, const float* __restrict__ Wo,
    const float* __restrict__ W1, const float* __restrict__ W2,
    uint16_t* __restrict__ wqkvT, uint16_t* __restrict__ woT,
    uint16_t* __restrict__ w1T, uint16_t* __restrict__ w2T) {
    int t = blockIdx.x * 256 + threadIdx.x;
    if (t < 49152) {                       // wqkvT[n][k], n in [0,384)
        int n = t >> 7, k = t & 127;
        const float* W = (n < 128) ? Wq : (n < 256) ? Wk : Wv;
        wqkvT[t] = f2bf(W[k * 128 + (n & 127)]);
    } else if (t < 65536) {                // woT[e][d] = Wo[d][e]
        int i = t - 49152; int e = i >> 7, d = i & 127;
        woT[i] = f2bf(Wo[d * 128 + e]);
    } else if (t < 131072) {               // w1T[f][e] = W1[e][f]
        int i = t - 65536; int f = i >> 7, e = i & 127;
        w1T[i] = f2bf(W1[e * 512 + f]);
    } else if (t < 196608) {               // w2T[e][f] = W2[f][e]
        int i = t - 131072; int e = i >> 9, f = i & 511;
        w2T[i] = f2bf(W2[f * 128 + e]);
    }
}

// ---------------------------------------------------------------- k_rms
__global__ __launch_bounds__(256) void k_rms(
    const float* __restrict__ x, const float* __restrict__ g,
    uint16_t* __restrict__ o) {
    int row = blockIdx.x * 4 + (threadIdx.x >> 6);
    int l = threadIdx.x & 63;
    float2 v = *(const float2*)(x + (size_t)row * 128 + l * 2);
    float ss = v.x * v.x + v.y * v.y;
    #pragma unroll
    for (int m = 32; m >= 1; m >>= 1) ss += __shfl_xor(ss, m, 64);
    float rs = rsqrtf(ss * (1.0f / 128.0f) + 1e-6f);
    float2 gv = *(const float2*)(g + l * 2);
    uint32_t lo = (uint32_t)f2bf(v.x * rs * gv.x) |
                  ((uint32_t)f2bf(v.y * rs * gv.y) << 16);
    *(uint32_t*)(o + (size_t)row * 128 + l * 2) = lo;
}

// ---------------------------------------------------------------- k_qkv
// [64 x 128] h-tile @ [128 x 384] Wqkv. 6 waves, each 64x64.
// Epilogue: sigq = sigmoid(q) (bf16), McatT[b][col][i] = [exp(k)*v | exp(k)].
__global__ __launch_bounds__(384) void k_qkv(
    const uint16_t* __restrict__ h, const uint16_t* __restrict__ wqkvT,
    uint16_t* __restrict__ sigq, uint16_t* __restrict__ mcatT) {
    __shared__ __align__(16) char sm[65536];
    uint16_t* Al = (uint16_t*)sm;   // 64 x 136 bf16
    float*    Pl = (float*)sm;      // 64 x 256 f32, after K-loop
    const int t = threadIdx.x;
    const int i0 = blockIdx.x * 64;
    for (int idx = t; idx < 1024; idx += 384) {
        int row = idx >> 4, c8 = (idx & 15) * 8;
        *(uint4*)&Al[row * 136 + c8] =
            *(const uint4*)(h + (size_t)(i0 + row) * 128 + c8);
    }
    __syncthreads();
    const int w = t >> 6, l = t & 63, ml = l & 15, qd = l >> 4;
    f32x4 acc[4][4];
    f32x4 zv = {0.f, 0.f, 0.f, 0.f};
    #pragma unroll
    for (int a = 0; a < 4; ++a)
        #pragma unroll
        for (int b = 0; b < 4; ++b) acc[a][b] = zv;
    #pragma unroll
    for (int kc = 0; kc < 4; ++kc) {
        short8 af[4], bfr[4];
        #pragma unroll
        for (int fm = 0; fm < 4; ++fm)
            af[fm] = *(const short8*)&Al[(fm * 16 + ml) * 136 + kc * 32 + qd * 8];
        #pragma unroll
        for (int fn = 0; fn < 4; ++fn)
            bfr[fn] = *(const short8*)(wqkvT + (w * 64 + fn * 16 + ml) * 128 + kc * 32 + qd * 8);
        #pragma unroll
        for (int fm = 0; fm < 4; ++fm)
            #pragma unroll
            for (int fn = 0; fn < 4; ++fn)
                acc[fm][fn] = mfma16(af[fm], bfr[fn], acc[fm][fn]);
    }
    __syncthreads();
    const int bb = i0 >> 12, il0 = i0 & 4095;
    if (w < 2) {       // q columns -> sigmoid, straight to global
        #pragma unroll
        for (int fm = 0; fm < 4; ++fm)
            #pragma unroll
            for (int fn = 0; fn < 4; ++fn)
                #pragma unroll
                for (int r = 0; r < 4; ++r) {
                    int row = fm * 16 + qd * 4 + r;
                    int col = w * 64 + fn * 16 + ml;
                    sigq[(size_t)(i0 + row) * 128 + col] =
                        f2bf(1.f / (1.f + __expf(-acc[fm][fn][r])));
                }
    } else {           // k -> exp(k) at Pl cols [0,128); v raw at [128,256)
        int half = (w < 4) ? 0 : 1;
        int cbase = (w - (half ? 4 : 2)) * 64;
        #pragma unroll
        for (int fm = 0; fm < 4; ++fm)
            #pragma unroll
            for (int fn = 0; fn < 4; ++fn)
                #pragma unroll
                for (int r = 0; r < 4; ++r) {
                    int row = fm * 16 + qd * 4 + r;
                    int col = cbase + fn * 16 + ml;
                    float vv = acc[fm][fn][r];
                    if (!half) vv = __expf(vv);
                    Pl[row * 256 + half * 128 + ((col + row) & 127)] = vv;
                }
    }
    __syncthreads();
    for (int idx = t; idx < 16384; idx += 384) {
        int cc = idx >> 6, il = idx & 63;
        int pc = ((cc & 127) + il) & 127;
        float ekw = Pl[il * 256 + pc];
        float val = (cc < 128) ? ekw * Pl[il * 256 + 128 + pc] : ekw;
        mcatT[((size_t)bb * 256 + cc) * 4096 + il0 + il] = f2bf(val);
    }
}

// ---------------------------------------------------------------- k_mega
// Fuses k_big + k_att + rmsnorm2. Per (j-tile of 32, batch):
//   P[32 x 256] = sum_i exp(c*dis[i][j]) * Mcat[i][col]   (full K=4096)
//   att = sigq * (P[:, :128] / P[:, 128:])                (bf16)
//   out1 = x + att @ Wo ; h2 = rmsnorm(out1, g_post)
// K-loop uses counted-wait barriers (lgkmcnt(0) only) so the dis prefetch
// (3 steps deep) and mcat B-prefetch (1 step deep) stay in flight across
// barriers. All prefetch state in NAMED registers (no spillable arrays).
__global__ __launch_bounds__(512) void k_mega(
    const float* __restrict__ dis, const uint16_t* __restrict__ mcatT,
    const float* __restrict__ alpha_p, const uint16_t* __restrict__ sigq,
    const uint16_t* __restrict__ woT, const float* __restrict__ x,
    const float* __restrict__ g_post,
    float* __restrict__ out1, uint16_t* __restrict__ h2) {
    __shared__ __align__(16) char sm[42496];
    uint16_t* Al0 = (uint16_t*)sm;           // 32 x 72 bf16 (4608 B)
    uint16_t* Al1 = (uint16_t*)(sm + 4608);  // 32 x 72 bf16 (4608 B)
    float*    P   = (float*)sm;              // 32 x 264 f32 (33792 B) [epilogue]
    uint16_t* Att = (uint16_t*)(sm + 33792); // 32 x 136 bf16 (8704 B) [epilogue]
    __shared__ float rowsum[32];

    const int t = threadIdx.x;
    const int j0 = blockIdx.x * 32;
    const int b  = blockIdx.y;
    const float c = -12.0f * alpha_p[0];     // log2(4096)=12
    const int w = t >> 6, l = t & 63, ml = l & 15, qd = l >> 4;
    const int il = t >> 3;                   // i-row 0..63 within K-step
    const int j4 = (t & 7) * 4;              // j column group
    const float* disb = dis + (size_t)b * 4096 * 4096 + j0;
    const uint16_t* mb = mcatT + (size_t)b * 256 * 4096;
    const int brow0 = (w * 32 + ml) * 4096;        // B row for bf0
    const int brow1 = (w * 32 + 16 + ml) * 4096;   // B row for bf1
    const int boff  = qd * 8;

    f32x4 acc00, acc01, acc10, acc11;
    f32x4 zv = {0.f, 0.f, 0.f, 0.f};
    acc00 = zv; acc01 = zv; acc10 = zv; acc11 = zv;

    // prologue: Al0 <- step 0; dis for steps 1,2 and B for step 0 in flight
    {
        float4 d0 = *(const float4*)(disb + (size_t)il * 4096 + j4);
        Al0[(j4 + 0) * 72 + il] = f2bf(__expf(c * d0.x));
        Al0[(j4 + 1) * 72 + il] = f2bf(__expf(c * d0.y));
        Al0[(j4 + 2) * 72 + il] = f2bf(__expf(c * d0.z));
        Al0[(j4 + 3) * 72 + il] = f2bf(__expf(c * d0.w));
    }
    float4 dO = *(const float4*)(disb + (size_t)(64 + il) * 4096 + j4);   // step 1
    float4 dE = *(const float4*)(disb + (size_t)(128 + il) * 4096 + j4);  // step 2
    short8 pb0 = *(const short8*)(mb + brow0 + boff);                     // B step 0
    short8 pb1 = *(const short8*)(mb + brow1 + boff);
    short8 pb2 = *(const short8*)(mb + brow0 + 32 + boff);
    short8 pb3 = *(const short8*)(mb + brow1 + 32 + boff);
    barrier_lgkm();

    for (int m = 0; m < 32; ++m) {
        // ------------- even step s = 2m : MFMA from Al0 -------------
        {
            short8 u0 = pb0, u1 = pb1, u2 = pb2, u3 = pb3;
            float4 du = dO;
            const int ig1 = (2 * m + 1) * 64;      // B prefetch: step 2m+1
            pb0 = *(const short8*)(mb + brow0 + ig1 + boff);
            pb1 = *(const short8*)(mb + brow1 + ig1 + boff);
            pb2 = *(const short8*)(mb + brow0 + ig1 + 32 + boff);
            pb3 = *(const short8*)(mb + brow1 + ig1 + 32 + boff);
            if (m < 31)                            // dis prefetch: step 2m+3
                dO = *(const float4*)(disb + (size_t)((2 * m + 3) * 64 + il) * 4096 + j4);
            short8 af0 = *(const short8*)&Al0[ml * 72 + boff];
            short8 af1 = *(const short8*)&Al0[(16 + ml) * 72 + boff];
            short8 ag0 = *(const short8*)&Al0[ml * 72 + 32 + boff];
            short8 ag1 = *(const short8*)&Al0[(16 + ml) * 72 + 32 + boff];
            acc00 = mfma16(af0, u0, acc00);
            acc01 = mfma16(af0, u1, acc01);
            acc10 = mfma16(af1, u0, acc10);
            acc11 = mfma16(af1, u1, acc11);
            acc00 = mfma16(ag0, u2, acc00);
            acc01 = mfma16(ag0, u3, acc01);
            acc10 = mfma16(ag1, u2, acc10);
            acc11 = mfma16(ag1, u3, acc11);
            // write Al1 <- exp(dis step 2m+1), loaded 2 steps ago
            Al1[(j4 + 0) * 72 + il] = f2bf(__expf(c * du.x));
            Al1[(j4 + 1) * 72 + il] = f2bf(__expf(c * du.y));
            Al1[(j4 + 2) * 72 + il] = f2bf(__expf(c * du.z));
            Al1[(j4 + 3) * 72 + il] = f2bf(__expf(c * du.w));
            barrier_lgkm();
        }
        // ------------- odd step s = 2m+1 : MFMA from Al1 -------------
        {
            short8 u0 = pb0, u1 = pb1, u2 = pb2, u3 = pb3;
            float4 du = dE;
            if (m < 31) {                          // B prefetch: step 2m+2
                const int ig2 = (2 * m + 2) * 64;
                pb0 = *(const short8*)(mb + brow0 + ig2 + boff);
                pb1 = *(const short8*)(mb + brow1 + ig2 + boff);
                pb2 = *(const short8*)(mb + brow0 + ig2 + 32 + boff);
                pb3 = *(const short8*)(mb + brow1 + ig2 + 32 + boff);
            }
            if (m < 30)                            // dis prefetch: step 2m+4
                dE = *(const float4*)(disb + (size_t)((2 * m + 4) * 64 + il) * 4096 + j4);
            short8 af0 = *(const short8*)&Al1[ml * 72 + boff];
            short8 af1 = *(const short8*)&Al1[(16 + ml) * 72 + boff];
            short8 ag0 = *(const short8*)&Al1[ml * 72 + 32 + boff];
            short8 ag1 = *(const short8*)&Al1[(16 + ml) * 72 + 32 + boff];
            acc00 = mfma16(af0, u0, acc00);
            acc01 = mfma16(af0, u1, acc01);
            acc10 = mfma16(af1, u0, acc10);
            acc11 = mfma16(af1, u1, acc11);
            acc00 = mfma16(ag0, u2, acc00);
            acc01 = mfma16(ag0, u3, acc01);
            acc10 = mfma16(ag1, u2, acc10);
            acc11 = mfma16(ag1, u3, acc11);
            // write Al0 <- exp(dis step 2m+2) (m=31: harmless garbage,
            // Al0 is dead after the loop and overwritten by P)
            Al0[(j4 + 0) * 72 + il] = f2bf(__expf(c * du.x));
            Al0[(j4 + 1) * 72 + il] = f2bf(__expf(c * du.y));
            Al0[(j4 + 2) * 72 + il] = f2bf(__expf(c * du.z));
            Al0[(j4 + 3) * 72 + il] = f2bf(__expf(c * du.w));
            barrier_lgkm();
        }
    }

    // ---- epilogue: merge w1/w2, att@Wo, residual, rmsnorm ----
    {
        const int colb = w * 32;
        #pragma unroll
        for (int r = 0; r < 4; ++r) {
            P[(qd * 4 + r) * 264 + colb + ml] = acc00[r];
            P[(qd * 4 + r) * 264 + colb + 16 + ml] = acc01[r];
            P[(16 + qd * 4 + r) * 264 + colb + ml] = acc10[r];
            P[(16 + qd * 4 + r) * 264 + colb + 16 + ml] = acc11[r];
        }
    }
    if (t < 32) rowsum[t] = 0.f;
    __syncthreads();
    {
        const uint16_t* sq = sigq + (size_t)(b * 4096 + j0) * 128;
        #pragma unroll
        for (int it = 0; it < 2; ++it) {
            int q = t + it * 512;
            int j = q >> 5, c4 = (q & 31) * 4;
            float4 w1v = *(const float4*)&P[j * 264 + c4];
            float4 w2v = *(const float4*)&P[j * 264 + 128 + c4];
            const uint16_t* sp = sq + j * 128 + c4;
            uint32_t lo = (uint32_t)f2bf(bf2f(sp[0]) * w1v.x / w2v.x) |
                          ((uint32_t)f2bf(bf2f(sp[1]) * w1v.y / w2v.y) << 16);
            uint32_t hi = (uint32_t)f2bf(bf2f(sp[2]) * w1v.z / w2v.z) |
                          ((uint32_t)f2bf(bf2f(sp[3]) * w1v.w / w2v.w) << 16);
            uint2 pk = {lo, hi};
            *(uint2*)&Att[j * 136 + c4] = pk;
        }
    }
    __syncthreads();
    f32x4 acc2a = zv, acc2b = zv;
    #pragma unroll
    for (int kc = 0; kc < 4; ++kc) {
        short8 af0 = *(const short8*)&Att[ml * 136 + kc * 32 + qd * 8];
        short8 af1 = *(const short8*)&Att[(16 + ml) * 136 + kc * 32 + qd * 8];
        short8 bf  = *(const short8*)(woT + (w * 16 + ml) * 128 + kc * 32 + qd * 8);
        acc2a = mfma16(af0, bf, acc2a);
        acc2b = mfma16(af1, bf, acc2b);
    }
    const int col = w * 16 + ml;
    const float gp = g_post[col];
    float ov0[4], ov1[4];
    #pragma unroll
    for (int r = 0; r < 4; ++r) {
        int rowl = qd * 4 + r;
        size_t o = (size_t)(b * 4096 + j0 + rowl) * 128 + col;
        float v = x[o] + acc2a[r];
        ov0[r] = v;
        out1[o] = v;
        float ss = v * v;
        ss += __shfl_xor(ss, 1, 64);
        ss += __shfl_xor(ss, 2, 64);
        ss += __shfl_xor(ss, 4, 64);
        ss += __shfl_xor(ss, 8, 64);
        if (ml == 0) atomicAdd(&rowsum[rowl], ss);
    }
    #pragma unroll
    for (int r = 0; r < 4; ++r) {
        int rowl = 16 + qd * 4 + r;
        size_t o = (size_t)(b * 4096 + j0 + rowl) * 128 + col;
        float v = x[o] + acc2b[r];
        ov1[r] = v;
        out1[o] = v;
        float ss = v * v;
        ss += __shfl_xor(ss, 1, 64);
        ss += __shfl_xor(ss, 2, 64);
        ss += __shfl_xor(ss, 4, 64);
        ss += __shfl_xor(ss, 8, 64);
        if (ml == 0) atomicAdd(&rowsum[rowl], ss);
    }
    __syncthreads();
    #pragma unroll
    for (int r = 0; r < 4; ++r) {
        int rowl = qd * 4 + r;
        float rs = rsqrtf(rowsum[rowl] * (1.f / 128.f) + 1e-6f);
        h2[(size_t)(b * 4096 + j0 + rowl) * 128 + col] = f2bf(ov0[r] * rs * gp);
    }
    #pragma unroll
    for (int r = 0; r < 4; ++r) {
        int rowl = 16 + qd * 4 + r;
        float rs = rsqrtf(rowsum[rowl] * (1.f / 128.f) + 1e-6f);
        h2[(size_t)(b * 4096 + j0 + rowl) * 128 + col] = f2bf(ov1[r] * rs * gp);
    }
}

// ---------------------------------------------------------------- k_ff
// Fused FFN: R = relu(h2 @ W1 + b1) kept in LDS (two 256-col halves),
// out = out1 + R @ W2 + b2. One block per 64 rows, 8 waves.
__global__ __launch_bounds__(512) void k_ff(
    const uint16_t* __restrict__ h2, const uint16_t* __restrict__ w1T,
    const float* __restrict__ b1, const uint16_t* __restrict__ w2T,
    const float* __restrict__ b2, const float* __restrict__ out1,
    float* __restrict__ out) {
    __shared__ __align__(16) uint16_t Al[64 * 136];   // 17408 B
    __shared__ __align__(16) uint16_t Rl[64 * 264];   // 33792 B
    const int t = threadIdx.x;
    const int i0 = blockIdx.x * 64;
    const int w = t >> 6, l = t & 63, ml = l & 15, qd = l >> 4;
    #pragma unroll
    for (int ii = 0; ii < 2; ++ii) {
        int idx = t + ii * 512;
        int row = idx >> 4, c8 = (idx & 15) * 8;
        *(uint4*)&Al[row * 136 + c8] =
            *(const uint4*)(h2 + (size_t)(i0 + row) * 128 + c8);
    }
    __syncthreads();
    const int wm = w >> 2, wn = w & 3;
    f32x4 zv = {0.f, 0.f, 0.f, 0.f};
    f32x4 a2[2][2];
    a2[0][0] = zv; a2[0][1] = zv; a2[1][0] = zv; a2[1][1] = zv;
    for (int hf = 0; hf < 2; ++hf) {
        if (hf) __syncthreads();           // phase-2 readers of Rl done
        // phase 1: R[:, hf*256 .. +256) = relu(h2 @ W1 + b1)
        f32x4 a1[4][2];
        #pragma unroll
        for (int fm = 0; fm < 4; ++fm) { a1[fm][0] = zv; a1[fm][1] = zv; }
        #pragma unroll
        for (int kc = 0; kc < 4; ++kc) {
            short8 af[4], bfr[2];
            #pragma unroll
            for (int fm = 0; fm < 4; ++fm)
                af[fm] = *(const short8*)&Al[(fm * 16 + ml) * 136 + kc * 32 + qd * 8];
            #pragma unroll
            for (int fn = 0; fn < 2; ++fn)
                bfr[fn] = *(const short8*)(w1T +
                    (size_t)(hf * 256 + w * 32 + fn * 16 + ml) * 128 + kc * 32 + qd * 8);
            #pragma unroll
            for (int fm = 0; fm < 4; ++fm)
                #pragma unroll
                for (int fn = 0; fn < 2; ++fn)
                    a1[fm][fn] = mfma16(af[fm], bfr[fn], a1[fm][fn]);
        }
        #pragma unroll
        for (int fm = 0; fm < 4; ++fm)
            #pragma unroll
            for (int fn = 0; fn < 2; ++fn) {
                int fcol = w * 32 + fn * 16 + ml;
                float bias = b1[hf * 256 + fcol];
                #pragma unroll
                for (int r = 0; r < 4; ++r) {
                    int row = fm * 16 + qd * 4 + r;
                    Rl[row * 264 + fcol] = f2bf(fmaxf(a1[fm][fn][r] + bias, 0.f));
                }
            }
        __syncthreads();
        // phase 2: accumulate R_half @ W2_half
        #pragma unroll
        for (int kc = 0; kc < 8; ++kc) {
            short8 af[2], bfr[2];
            #pragma unroll
            for (int fm = 0; fm < 2; ++fm)
                af[fm] = *(const short8*)&Rl[(wm * 32 + fm * 16 + ml) * 264 + kc * 32 + qd * 8];
            #pragma unroll
            for (int fn = 0; fn < 2; ++fn)
                bfr[fn] = *(const short8*)(w2T +
                    (size_t)(wn * 32 + fn * 16 + ml) * 512 + hf * 256 + kc * 32 + qd * 8);
            #pragma unroll
            for (int fm = 0; fm < 2; ++fm)
                #pragma unroll
                for (int fn = 0; fn < 2; ++fn)
                    a2[fm][fn] = mfma16(af[fm], bfr[fn], a2[fm][fn]);
        }
    }
    #pragma unroll
    for (int fm = 0; fm < 2; ++fm)
        #pragma unroll
        for (int fn = 0; fn < 2; ++fn) {
            int colo = wn * 32 + fn * 16 + ml;
            float bias = b2[colo];
            #pragma unroll
            for (int r = 0; r < 4; ++r) {
                int rowl = wm * 32 + fm * 16 + qd * 4 + r;
                size_t o = (size_t)(i0 + rowl) * 128 + colo;
                out[o] = out1[o] + bias + a2[fm][fn][r];
            }
        }
}

// ---------------------------------------------------------------- launch
extern "C" void kernel_launch(void* const* d_in, const int* in_sizes, int n_in,
                              void* d_out, int out_size, void* d_ws, size_t ws_size,
                              hipStream_t stream) {
    (void)in_sizes; (void)n_in; (void)out_size; (void)ws_size;
    const float* x      = (const float*)d_in[0];
    const float* dis    = (const float*)d_in[1];
    const float* g_in   = (const float*)d_in[2];
    const float* g_post = (const float*)d_in[3];
    const float* Wq     = (const float*)d_in[4];
    const float* Wk     = (const float*)d_in[5];
    const float* Wv     = (const float*)d_in[6];
    const float* alpha  = (const float*)d_in[7];
    const float* Wo     = (const float*)d_in[8];
    const float* W1     = (const float*)d_in[9];
    const float* b1     = (const float*)d_in[10];
    const float* W2     = (const float*)d_in[11];
    const float* b2     = (const float*)d_in[12];
    float* out = (float*)d_out;

    char* ws = (char*)d_ws;
    size_t off = 0;
    auto take = [&](size_t bytes) -> char* {
        char* p = ws + off;
        off += (bytes + 255) & ~(size_t)255;
        return p;
    };
    uint16_t* h     = (uint16_t*)take(16384ull * 128 * 2);     //  4 MB
    uint16_t* wqkvT = (uint16_t*)take(384ull * 128 * 2);
    uint16_t* woT   = (uint16_t*)take(128ull * 128 * 2);
    uint16_t* w1T   = (uint16_t*)take(512ull * 128 * 2);
    uint16_t* w2T   = (uint16_t*)take(128ull * 512 * 2);
    uint16_t* sigq  = (uint16_t*)take(16384ull * 128 * 2);     //  4 MB
    uint16_t* mcatT = (uint16_t*)take(4ull * 256 * 4096 * 2);  //  8 MB
    float*    out1  = (float*)take(16384ull * 128 * 4);        //  8 MB
    uint16_t* h2    = (uint16_t*)take(16384ull * 128 * 2);     //  4 MB

    k_prep<<<768, 256, 0, stream>>>(Wq, Wk, Wv, Wo, W1, W2, wqkvT, woT, w1T, w2T);
    k_rms<<<4096, 256, 0, stream>>>(x, g_in, h);
    k_qkv<<<256, 384, 0, stream>>>(h, wqkvT, sigq, mcatT);
    k_mega<<<dim3(128, 4), 512, 0, stream>>>(dis, mcatT, alpha, sigq, woT, x, g_post, out1, h2);
    k_ff<<<256, 512, 0, stream>>>(h2, w1T, b1, w2T, b2, out1, out);
}